// Round 14
// baseline (1234.889 us; speedup 1.0000x reference)
//
#include <hip/hip_runtime.h>

#define WG 256

#define MLP_FMA16(ACC, A, W) do { \
    ACC[0][0]=fmaf(A.x,W.x,ACC[0][0]); ACC[0][1]=fmaf(A.x,W.y,ACC[0][1]); \
    ACC[0][2]=fmaf(A.x,W.z,ACC[0][2]); ACC[0][3]=fmaf(A.x,W.w,ACC[0][3]); \
    ACC[1][0]=fmaf(A.y,W.x,ACC[1][0]); ACC[1][1]=fmaf(A.y,W.y,ACC[1][1]); \
    ACC[1][2]=fmaf(A.y,W.z,ACC[1][2]); ACC[1][3]=fmaf(A.y,W.w,ACC[1][3]); \
    ACC[2][0]=fmaf(A.z,W.x,ACC[2][0]); ACC[2][1]=fmaf(A.z,W.y,ACC[2][1]); \
    ACC[2][2]=fmaf(A.z,W.z,ACC[2][2]); ACC[2][3]=fmaf(A.z,W.w,ACC[2][3]); \
    ACC[3][0]=fmaf(A.w,W.x,ACC[3][0]); ACC[3][1]=fmaf(A.w,W.y,ACC[3][1]); \
    ACC[3][2]=fmaf(A.w,W.z,ACC[3][2]); ACC[3][3]=fmaf(A.w,W.w,ACC[3][3]); \
} while (0)

// ===== unified fused layer kernel ==========================================
// Node part: O = concat(inA[gidxA?], AGGR) @ W1+b1 |> relu |> @W2+b2 (+skip)
// AGGR (HAS_AGGR): computed IN-KERNEL per own 64 rows: wave-per-node slot
//   gather (shfl-index trick) into registers, deposited at phase-B staging.
// Msg tail (MSG_DOUT=64): outM = relu(O @ M1 + mb1) @ M2 + mb2 (rows < msgN)
// Msg tail (MSG_DOUT=2):  decode. MSG_DOUT=0: node-only.
// Round-12 MLP core: 64-row blocks, 256 thr, 4x4 acc, ~34.8 KB LDS -> 4 blk/CU.
template<int DINA, bool HAS_AGGR, bool REMAPB, bool HAS_SKIP, bool GATHER_A,
         int MSG_DOUT, bool PARTIAL_MSG, bool WRITE_OUT1>
__global__ __launch_bounds__(WG)
void mlp2_fused(const float* __restrict__ inA, const int* __restrict__ gidxA,
                const int* __restrict__ deg, const int* __restrict__ slots,
                int cap, const int* __restrict__ remapB,
                const float* __restrict__ tab,
                const float* __restrict__ W1, const float* __restrict__ b1,
                const float* __restrict__ W2, const float* __restrict__ b2,
                const float* __restrict__ skip, float* __restrict__ out1,
                const float* __restrict__ M1, const float* __restrict__ mb1,
                const float* __restrict__ M2, const float* __restrict__ mb2,
                float* __restrict__ outM, int msgN, int n)
{
    constexpr int XP = 68;                           // b128-aligned, conflict-free
    __shared__ __align__(16) float sXT[64][XP];      // X^T phases / H^T / O^T / H2^T
    __shared__ __align__(16) float sW[64 * 64];      // W1 phases / W2 / M1 / M2
    __shared__ float sb[128];
    __shared__ float sW2d[128];                      // decode W2 (64x2)
    __shared__ float sb2d[2];

    const int tid = threadIdx.x;
    const int tx = tid & 15, ty = tid >> 4;
    const int c0 = tx * 4, r0 = ty * 4;
    const int row0 = blockIdx.x * 64;
    const int lane = tid & 63;
    const int wv = tid >> 6;                         // wave 0..3
    const int kq0 = wv * 4;

    // ---- stage W1 phase A (DINA rows), biases
    for (int i = tid * 4; i < DINA * 64; i += WG * 4)
        *(float4*)&sW[i] = *(const float4*)&W1[i];
    if (tid < 64) sb[tid] = b1[tid];
    else if (tid < 128) sb[tid] = b2[tid - 64];

    // ---- stage X^T phase A (lane = row, conflict-free)
    {
        const int rg = min(row0 + lane, n - 1);
        const int ra = GATHER_A ? gidxA[rg] : rg;
        const float* pA = inA + (size_t)ra * DINA;
        #pragma unroll
        for (int kq = kq0; kq < DINA; kq += 16) {
            const float4 v = *(const float4*)(pA + kq);
            sXT[kq + 0][lane] = v.x; sXT[kq + 1][lane] = v.y;
            sXT[kq + 2][lane] = v.z; sXT[kq + 3][lane] = v.w;
        }
    }

    // ---- in-kernel aggregation: wave w gathers nodes row0+w*16 .. +15
    float av[16];
    if constexpr (HAS_AGGR) {
        #pragma unroll
        for (int i = 0; i < 16; ++i) {
            const int node = min(row0 + wv * 16 + i, n - 1);
            const int d = min(deg[node], cap);
            const int* sl = slots + (size_t)node * cap;
            int myidx = 0;
            if (lane < d) {
                myidx = sl[lane];
                if (REMAPB) myidx = remapB[myidx];
            }
            float a0 = 0.f, a1 = 0.f, a2 = 0.f, a3 = 0.f;
            int j = 0;
            for (; j + 3 < d; j += 4) {
                const int t0 = __shfl(myidx, j + 0);
                const int t1 = __shfl(myidx, j + 1);
                const int t2 = __shfl(myidx, j + 2);
                const int t3 = __shfl(myidx, j + 3);
                a0 += tab[(size_t)t0 * 64 + lane];
                a1 += tab[(size_t)t1 * 64 + lane];
                a2 += tab[(size_t)t2 * 64 + lane];
                a3 += tab[(size_t)t3 * 64 + lane];
            }
            for (; j < d; ++j) {
                const int t = __shfl(myidx, j);
                a0 += tab[(size_t)t * 64 + lane];
            }
            av[i] = (a0 + a1) + (a2 + a3);
        }
    }
    __syncthreads();

    // ---- GEMM1 phase A
    float acc[4][4] = {};
    #pragma unroll 8
    for (int k = 0; k < DINA; ++k) {
        const float4 a = *(const float4*)&sXT[k][r0];
        const float4 w = *(const float4*)&sW[k * 64 + c0];
        MLP_FMA16(acc, a, w);
    }

    // ---- GEMM1 phase B: AGGR against W1 rows DINA..DINA+63
    if constexpr (HAS_AGGR) {
        __syncthreads();
        for (int i = tid * 4; i < 64 * 64; i += WG * 4)
            *(float4*)&sW[i] = *(const float4*)&W1[DINA * 64 + i];
        #pragma unroll
        for (int i = 0; i < 16; ++i)
            sXT[lane][wv * 16 + i] = av[i];    // feature=lane, row=wv*16+i
        __syncthreads();
        #pragma unroll 8
        for (int k = 0; k < 64; ++k) {
            const float4 a = *(const float4*)&sXT[k][r0];
            const float4 w = *(const float4*)&sW[k * 64 + c0];
            MLP_FMA16(acc, a, w);
        }
    }
    __syncthreads();

    // ---- stage W2; write H^T
    for (int i = tid * 4; i < 64 * 64; i += WG * 4)
        *(float4*)&sW[i] = *(const float4*)&W2[i];
    #pragma unroll
    for (int j = 0; j < 4; ++j) {
        const float bj = sb[c0 + j];
        *(float4*)&sXT[c0 + j][r0] = make_float4(
            fmaxf(acc[0][j] + bj, 0.f), fmaxf(acc[1][j] + bj, 0.f),
            fmaxf(acc[2][j] + bj, 0.f), fmaxf(acc[3][j] + bj, 0.f));
    }
    __syncthreads();

    // ---- GEMM2
    float acc2[4][4] = {};
    #pragma unroll 8
    for (int k = 0; k < 64; ++k) {
        const float4 a = *(const float4*)&sXT[k][r0];
        const float4 w = *(const float4*)&sW[k * 64 + c0];
        MLP_FMA16(acc2, a, w);
    }

    // ---- O = acc2 + b2 (+skip); write out1
    float ofull[4][4];
    #pragma unroll
    for (int i = 0; i < 4; ++i) {
        const int row = row0 + r0 + i;
        float4 s = make_float4(0.f, 0.f, 0.f, 0.f);
        if (HAS_SKIP && row < n) s = *(const float4*)&skip[(size_t)row * 64 + c0];
        ofull[i][0] = acc2[i][0] + sb[64 + c0 + 0] + s.x;
        ofull[i][1] = acc2[i][1] + sb[64 + c0 + 1] + s.y;
        ofull[i][2] = acc2[i][2] + sb[64 + c0 + 2] + s.z;
        ofull[i][3] = acc2[i][3] + sb[64 + c0 + 3] + s.w;
        if (WRITE_OUT1 && row < n)
            *(float4*)&out1[(size_t)row * 64 + c0] =
                make_float4(ofull[i][0], ofull[i][1], ofull[i][2], ofull[i][3]);
    }

    // ================= msg tail =================
    if constexpr (MSG_DOUT > 0) {
        if (!PARTIAL_MSG || row0 < msgN) {   // block-uniform
            __syncthreads();
            for (int i = tid * 4; i < 64 * 64; i += WG * 4)
                *(float4*)&sW[i] = *(const float4*)&M1[i];
            if constexpr (MSG_DOUT == 64) {
                if (tid < 64) sb[tid] = mb1[tid];
                else if (tid < 128) sb[tid] = mb2[tid - 64];
            } else {
                if (tid < 64) sb[tid] = mb1[tid];
                else if (tid < 192) sW2d[tid - 64] = M2[tid - 64];
                else if (tid < 194) sb2d[tid - 192] = mb2[tid - 192];
            }
            #pragma unroll
            for (int j = 0; j < 4; ++j)
                *(float4*)&sXT[c0 + j][r0] =
                    make_float4(ofull[0][j], ofull[1][j], ofull[2][j], ofull[3][j]);
            __syncthreads();

            // GEMM3: H2 = relu(O @ M1 + mb1)
            float acc3[4][4] = {};
            #pragma unroll 8
            for (int k = 0; k < 64; ++k) {
                const float4 a = *(const float4*)&sXT[k][r0];
                const float4 w = *(const float4*)&sW[k * 64 + c0];
                MLP_FMA16(acc3, a, w);
            }
            __syncthreads();
            if constexpr (MSG_DOUT == 64) {
                for (int i = tid * 4; i < 64 * 64; i += WG * 4)
                    *(float4*)&sW[i] = *(const float4*)&M2[i];
            }
            #pragma unroll
            for (int j = 0; j < 4; ++j) {
                const float bj = sb[c0 + j];
                *(float4*)&sXT[c0 + j][r0] = make_float4(
                    fmaxf(acc3[0][j] + bj, 0.f), fmaxf(acc3[1][j] + bj, 0.f),
                    fmaxf(acc3[2][j] + bj, 0.f), fmaxf(acc3[3][j] + bj, 0.f));
            }
            __syncthreads();

            if constexpr (MSG_DOUT == 64) {
                float accM[4][4] = {};
                #pragma unroll 8
                for (int k = 0; k < 64; ++k) {
                    const float4 a = *(const float4*)&sXT[k][r0];
                    const float4 w = *(const float4*)&sW[k * 64 + c0];
                    MLP_FMA16(accM, a, w);
                }
                #pragma unroll
                for (int i = 0; i < 4; ++i) {
                    const int row = row0 + r0 + i;
                    if (row < msgN)
                        *(float4*)&outM[(size_t)row * 64 + c0] =
                            make_float4(accM[i][0] + sb[64 + c0 + 0],
                                        accM[i][1] + sb[64 + c0 + 1],
                                        accM[i][2] + sb[64 + c0 + 2],
                                        accM[i][3] + sb[64 + c0 + 3]);
                }
            } else {
                // decode: 128 threads: (row,col)=(tid>>1, tid&1)
                if (tid < 128) {
                    const int lr = tid >> 1, col = tid & 1;
                    float o0 = sb2d[col], o1 = 0.0f;
                    #pragma unroll 8
                    for (int k = 0; k < 64; k += 2) {
                        o0 = fmaf(sXT[k][lr],     sW2d[k * 2 + col],       o0);
                        o1 = fmaf(sXT[k + 1][lr], sW2d[(k + 1) * 2 + col], o1);
                    }
                    const int row = row0 + lr;
                    if (row < msgN) outM[(size_t)row * 2 + col] = o0 + o1;
                }
            }
        }
    }
}

// ------------- XCD-partitioned slot binning --------------------------------
__global__ __launch_bounds__(WG)
void slot_fill_xcd_k(const int* __restrict__ s, const int* __restrict__ r,
                     int* __restrict__ cursor, int* __restrict__ slots,
                     int cap, int E, int n)
{
    const int xcd = blockIdx.x & 7;
    const int w   = blockIdx.x >> 3;
    const int W   = gridDim.x >> 3;
    const int lo  = (int)(((long)n * xcd) >> 3);
    const int hi  = (int)(((long)n * (xcd + 1)) >> 3);
    const int chunk = (E + W - 1) / W;
    const int e0 = w * chunk;
    const int e1 = min(E, e0 + chunk);
    for (int e = e0 + (int)threadIdx.x; e < e1; e += WG) {
        const int v = __builtin_nontemporal_load(&r[e]);
        if (v >= lo && v < hi) {
            const int sv = __builtin_nontemporal_load(&s[e]);
            const int p = atomicAdd(&cursor[v], 1);
            if (p < cap) slots[(size_t)v * cap + p] = sv;
        }
    }
}

extern "C" void kernel_launch(void* const* d_in, const int* in_sizes, int n_in,
                              void* d_out, int out_size, void* d_ws, size_t ws_size,
                              hipStream_t stream)
{
    const float* x    = (const float*)d_in[0];
    const float* We1  = (const float*)d_in[1];
    const float* be1  = (const float*)d_in[2];
    const float* We2  = (const float*)d_in[3];
    const float* be2  = (const float*)d_in[4];
    const float* Wm1  = (const float*)d_in[5];
    const float* bm1  = (const float*)d_in[6];
    const float* Wm2  = (const float*)d_in[7];
    const float* bm2  = (const float*)d_in[8];
    const float* Wn1  = (const float*)d_in[9];
    const float* bn1  = (const float*)d_in[10];
    const float* Wn2  = (const float*)d_in[11];
    const float* bn2  = (const float*)d_in[12];
    const float* Wd1  = (const float*)d_in[13];
    const float* bd1  = (const float*)d_in[14];
    const float* Wd2  = (const float*)d_in[15];
    const float* bd2  = (const float*)d_in[16];
    const int* s_fine = (const int*)d_in[17];
    const int* r_fine = (const int*)d_in[18];
    const int* s_ds   = (const int*)d_in[19];
    const int* r_ds   = (const int*)d_in[20];
    const int* s_p    = (const int*)d_in[21];
    const int* r_p    = (const int*)d_in[22];
    const int* s_us   = (const int*)d_in[23];
    const int* r_us   = (const int*)d_in[24];
    const int* uppool   = (const int*)d_in[25];
    const int* downpool = (const int*)d_in[26];

    const int N   = in_sizes[0] / 16;
    const int E   = in_sizes[17];
    const int EDS = in_sizes[19];
    const int EP  = in_sizes[21];
    const int EUS = in_sizes[23];
    const int NP  = in_sizes[26];

    const int CAP_FINE = 48, CAP_DS = 32, CAP_PP = 48, CAP_US = 32;

    // ---- workspace (same 156MB footprint proven in rounds 6-12) ----
    float* B0  = (float*)d_ws;
    float* B1  = B0 + (size_t)N * 64;
    float* B2  = B1 + (size_t)N * 64;
    float* B3  = B2 + (size_t)N * 64;
    float* HPa = B3 + (size_t)N * 64;
    float* HPb = HPa + (size_t)NP * 64;
    int* ip = (int*)(HPb + (size_t)NP * 64);
    auto alloc_i = [&](size_t n) { int* p = ip; ip += n; return p; };
    int* cur_fine = alloc_i(N);
    int* cur_ds   = alloc_i(N);
    int* cur_pp   = alloc_i(NP);
    int* cur_us   = alloc_i(NP);
    int* sl_fine  = alloc_i((size_t)N * CAP_FINE);
    int* sl_ds    = alloc_i((size_t)N * CAP_DS);
    int* sl_pp    = alloc_i((size_t)NP * CAP_PP);
    int* sl_us    = alloc_i((size_t)NP * CAP_US);

    const int gN  = (N + 63) / 64;
    const int gNP = (NP + 63) / 64;

    // ---- fills (XCD-partitioned)
    hipMemsetAsync(cur_fine, 0, (size_t)(2 * N + 2 * NP) * sizeof(int), stream);
    slot_fill_xcd_k<<<2048, WG, 0, stream>>>(s_fine, r_fine, cur_fine, sl_fine, CAP_FINE, E,   N);
    slot_fill_xcd_k<<<1024, WG, 0, stream>>>(s_ds,   r_ds,   cur_ds,   sl_ds,   CAP_DS,   EDS, N);
    slot_fill_xcd_k<<<512,  WG, 0, stream>>>(s_p,    r_p,    cur_pp,   sl_pp,   CAP_PP,   EP,  NP);
    slot_fill_xcd_k<<<512,  WG, 0, stream>>>(s_us,   r_us,   cur_us,   sl_us,   CAP_US,   EUS, NP);

    // Buffer plan (tab never aliases any output of the same kernel):
    // h0=B0 msg0=B1 | h1=B2 msg1=B0 | h2(skip)=B1 msg2=B2(<NP) | g=B3 |
    // msg3=HPa | hp1=HPb msg4=B2 | hp2=HPa msg5=HPb | g'=B3 msg6=B2 |
    // h7=B0 | msg7=B3 | out

    // ---- F_enc: encode + msg0 -> h0=B0, msg0=B1
    mlp2_fused<16,false,false,false,false,64,false,true><<<gN,WG,0,stream>>>(
        x,nullptr, nullptr,nullptr,0,nullptr, nullptr,
        We1,be1,We2,be2, nullptr,B0,
        Wm1+0*4096,bm1+0*64,Wm2+0*4096,bm2+0*64, B1, N, N);

    // ---- F_n0m1: node0(inA=B0, aggr fine tab=B1) -> h1=B2 ; msg1=B0
    mlp2_fused<64,true,false,false,false,64,false,true><<<gN,WG,0,stream>>>(
        B0,nullptr, cur_fine,sl_fine,CAP_FINE,nullptr, B1,
        Wn1+0*8192,bn1+0*64,Wn2+0*4096,bn2+0*64, nullptr,B2,
        Wm1+1*4096,bm1+1*64,Wm2+1*4096,bm2+1*64, B0, N, N);

    // ---- F_n1m2: node1(inA=B2, aggr fine tab=B0) -> h2=B1 (skip) ; msg2=B2 (<NP)
    mlp2_fused<64,true,false,false,false,64,true,true><<<gN,WG,0,stream>>>(
        B2,nullptr, cur_fine,sl_fine,CAP_FINE,nullptr, B0,
        Wn1+1*8192,bn1+1*64,Wn2+1*4096,bn2+1*64, nullptr,B1,
        Wm1+2*4096,bm1+2*64,Wm2+2*4096,bm2+2*64, B2, NP, N);

    // ---- N2: node2(inA=B1[uppool], aggr ds remap uppool tab=B2) -> g=B3
    mlp2_fused<64,true,true,false,true,0,false,true><<<gN,WG,0,stream>>>(
        B1,uppool, cur_ds,sl_ds,CAP_DS,uppool, B2,
        Wn1+2*8192,bn1+2*64,Wn2+2*4096,bn2+2*64, nullptr,B3,
        nullptr,nullptr,nullptr,nullptr, nullptr, 0, N);

    // ---- M3: msg3 over g[downpool] -> HPa
    mlp2_fused<64,false,false,false,true,0,false,true><<<gNP,WG,0,stream>>>(
        B3,downpool, nullptr,nullptr,0,nullptr, nullptr,
        Wm1+3*4096,bm1+3*64,Wm2+3*4096,bm2+3*64, nullptr,HPa,
        nullptr,nullptr,nullptr,nullptr, nullptr, 0, NP);

    // ---- F_n3m4: node3(inA=B3[downpool], aggr pp tab=HPa) -> hp1=HPb ; msg4=B2
    mlp2_fused<64,true,false,false,true,64,false,true><<<gNP,WG,0,stream>>>(
        B3,downpool, cur_pp,sl_pp,CAP_PP,nullptr, HPa,
        Wn1+3*8192,bn1+3*64,Wn2+3*4096,bn2+3*64, nullptr,HPb,
        Wm1+4*4096,bm1+4*64,Wm2+4*4096,bm2+4*64, B2, NP, NP);

    // ---- F_n4m5: node4(inA=HPb, aggr pp tab=B2) -> hp2=HPa ; msg5=HPb
    mlp2_fused<64,true,false,false,false,64,false,true><<<gNP,WG,0,stream>>>(
        HPb,nullptr, cur_pp,sl_pp,CAP_PP,nullptr, B2,
        Wn1+4*8192,bn1+4*64,Wn2+4*4096,bn2+4*64, nullptr,HPa,
        Wm1+5*4096,bm1+5*64,Wm2+5*4096,bm2+5*64, HPb, NP, NP);

    // ---- F_n5m6: node5(inA=HPa[downpool], aggr us remap downpool tab=HPb)
    //              -> g'=B3 ; msg6=B2
    mlp2_fused<64,true,true,false,true,64,false,true><<<gNP,WG,0,stream>>>(
        HPa,downpool, cur_us,sl_us,CAP_US,downpool, HPb,
        Wn1+5*8192,bn1+5*64,Wn2+5*4096,bn2+5*64, nullptr,B3,
        Wm1+6*4096,bm1+6*64,Wm2+6*4096,bm2+6*64, B2, NP, NP);

    // ---- F_n6: node6(inA=B3[uppool], aggr fine remap uppool tab=B2, +skip B1)
    //            -> h7=B0  (node-only)
    mlp2_fused<64,true,true,true,true,0,false,true><<<gN,WG,0,stream>>>(
        B3,uppool, cur_fine,sl_fine,CAP_FINE,uppool, B2,
        Wn1+6*8192,bn1+6*64,Wn2+6*4096,bn2+6*64, B1,B0,
        nullptr,nullptr,nullptr,nullptr, nullptr, 0, N);

    // ---- M7: msg7 over h7 -> B3
    mlp2_fused<64,false,false,false,false,0,false,true><<<gN,WG,0,stream>>>(
        B0,nullptr, nullptr,nullptr,0,nullptr, nullptr,
        Wm1+7*4096,bm1+7*64,Wm2+7*4096,bm2+7*64, nullptr,B3,
        nullptr,nullptr,nullptr,nullptr, nullptr, 0, N);

    // ---- F_n7dec: node7(inA=B0, aggr fine tab=B3, +skip B1) ; decode -> d_out
    mlp2_fused<64,true,false,true,false,2,false,false><<<gN,WG,0,stream>>>(
        B0,nullptr, cur_fine,sl_fine,CAP_FINE,nullptr, B3,
        Wn1+7*8192,bn1+7*64,Wn2+7*4096,bn2+7*64, B1,nullptr,
        Wd1,bd1,Wd2,bd2, (float*)d_out, N, N);
}

// Round 15
// 1100.942 us; speedup vs baseline: 1.1217x; 1.1217x over previous
//
#include <hip/hip_runtime.h>

#define WG 256

#define MLP_FMA16(ACC, A, W) do { \
    ACC[0][0]=fmaf(A.x,W.x,ACC[0][0]); ACC[0][1]=fmaf(A.x,W.y,ACC[0][1]); \
    ACC[0][2]=fmaf(A.x,W.z,ACC[0][2]); ACC[0][3]=fmaf(A.x,W.w,ACC[0][3]); \
    ACC[1][0]=fmaf(A.y,W.x,ACC[1][0]); ACC[1][1]=fmaf(A.y,W.y,ACC[1][1]); \
    ACC[1][2]=fmaf(A.y,W.z,ACC[1][2]); ACC[1][3]=fmaf(A.y,W.w,ACC[1][3]); \
    ACC[2][0]=fmaf(A.z,W.x,ACC[2][0]); ACC[2][1]=fmaf(A.z,W.y,ACC[2][1]); \
    ACC[2][2]=fmaf(A.z,W.z,ACC[2][2]); ACC[2][3]=fmaf(A.z,W.w,ACC[2][3]); \
    ACC[3][0]=fmaf(A.w,W.x,ACC[3][0]); ACC[3][1]=fmaf(A.w,W.y,ACC[3][1]); \
    ACC[3][2]=fmaf(A.w,W.z,ACC[3][2]); ACC[3][3]=fmaf(A.w,W.w,ACC[3][3]); \
} while (0)

// =============== fused: node-MLP (+out1) then msg-MLP of next layer =========
// Round-12 structure (64-row blocks, 256 thr, 4x4 acc) BUT weights are read
// directly from global (L1/L2-resident: every block reads the same 16-32 KB).
// -> only 1 ds_read_b128 per k-step (LDS pipe demand halved, ceiling ~70 TF)
// -> LDS ~18.4 KB -> 8 blocks/CU (was 4): double the barrier-shadow overlap.
template<int DINA, bool HAS_B, bool HAS_SKIP, bool GATHER_A,
         int MSG_DOUT, bool PARTIAL_MSG, bool WRITE_OUT1>
__global__ __launch_bounds__(WG)
void mlp2_fused(const float* __restrict__ inA, const int* __restrict__ gidxA,
                const float* __restrict__ inB,
                const float* __restrict__ W1, const float* __restrict__ b1,
                const float* __restrict__ W2, const float* __restrict__ b2,
                const float* __restrict__ skip, float* __restrict__ out1,
                const float* __restrict__ M1, const float* __restrict__ mb1,
                const float* __restrict__ M2, const float* __restrict__ mb2,
                float* __restrict__ outM, int msgN, int n)
{
    constexpr int XP = 68;                           // b128-aligned, conflict-free
    __shared__ __align__(16) float sXT[64][XP];      // X^T phases / H^T / O^T / H2^T
    __shared__ float sb[128];
    __shared__ float sW2d[128];                      // decode W2 (64x2)
    __shared__ float sb2d[2];

    const int tid = threadIdx.x;
    const int tx = tid & 15, ty = tid >> 4;
    const int c0 = tx * 4, r0 = ty * 4;
    const int row0 = blockIdx.x * 64;
    const int lrow = tid & 63;
    const int kq0 = (tid >> 6) * 4;

    // ---- biases
    if (tid < 64) sb[tid] = b1[tid];
    else if (tid < 128) sb[tid] = b2[tid - 64];

    // ---- stage X^T phase A (lane = row, conflict-free)
    {
        const int rg = min(row0 + lrow, n - 1);
        const int ra = GATHER_A ? gidxA[rg] : rg;
        const float* pA = inA + (size_t)ra * DINA;
        #pragma unroll
        for (int kq = kq0; kq < DINA; kq += 16) {
            const float4 v = *(const float4*)(pA + kq);
            sXT[kq + 0][lrow] = v.x; sXT[kq + 1][lrow] = v.y;
            sXT[kq + 2][lrow] = v.z; sXT[kq + 3][lrow] = v.w;
        }
    }
    __syncthreads();

    // ---- GEMM1 phase A (W1 direct from global)
    float acc[4][4] = {};
    #pragma unroll 8
    for (int k = 0; k < DINA; ++k) {
        const float4 a = *(const float4*)&sXT[k][r0];
        const float4 w = *(const float4*)&W1[k * 64 + c0];
        MLP_FMA16(acc, a, w);
    }

    // ---- GEMM1 phase B: inB against W1 rows DINA..DINA+63
    if constexpr (HAS_B) {
        __syncthreads();
        {
            const int rg = min(row0 + lrow, n - 1);
            const float* pB = inB + (size_t)rg * 64;
            #pragma unroll
            for (int kq = kq0; kq < 64; kq += 16) {
                const float4 v = *(const float4*)(pB + kq);
                sXT[kq + 0][lrow] = v.x; sXT[kq + 1][lrow] = v.y;
                sXT[kq + 2][lrow] = v.z; sXT[kq + 3][lrow] = v.w;
            }
        }
        __syncthreads();
        #pragma unroll 8
        for (int k = 0; k < 64; ++k) {
            const float4 a = *(const float4*)&sXT[k][r0];
            const float4 w = *(const float4*)&W1[(DINA + k) * 64 + c0];
            MLP_FMA16(acc, a, w);
        }
    }
    __syncthreads();

    // ---- write H^T
    #pragma unroll
    for (int j = 0; j < 4; ++j) {
        const float bj = sb[c0 + j];
        *(float4*)&sXT[c0 + j][r0] = make_float4(
            fmaxf(acc[0][j] + bj, 0.f), fmaxf(acc[1][j] + bj, 0.f),
            fmaxf(acc[2][j] + bj, 0.f), fmaxf(acc[3][j] + bj, 0.f));
    }
    __syncthreads();

    // ---- GEMM2 (W2 direct)
    float acc2[4][4] = {};
    #pragma unroll 8
    for (int k = 0; k < 64; ++k) {
        const float4 a = *(const float4*)&sXT[k][r0];
        const float4 w = *(const float4*)&W2[k * 64 + c0];
        MLP_FMA16(acc2, a, w);
    }

    // ---- O = acc2 + b2 (+skip); write out1
    float ofull[4][4];
    #pragma unroll
    for (int i = 0; i < 4; ++i) {
        const int row = row0 + r0 + i;
        float4 s = make_float4(0.f, 0.f, 0.f, 0.f);
        if (HAS_SKIP && row < n) s = *(const float4*)&skip[(size_t)row * 64 + c0];
        ofull[i][0] = acc2[i][0] + sb[64 + c0 + 0] + s.x;
        ofull[i][1] = acc2[i][1] + sb[64 + c0 + 1] + s.y;
        ofull[i][2] = acc2[i][2] + sb[64 + c0 + 2] + s.z;
        ofull[i][3] = acc2[i][3] + sb[64 + c0 + 3] + s.w;
        if (WRITE_OUT1 && row < n)
            *(float4*)&out1[(size_t)row * 64 + c0] =
                make_float4(ofull[i][0], ofull[i][1], ofull[i][2], ofull[i][3]);
    }

    // ================= msg tail =================
    if constexpr (MSG_DOUT > 0) {
        if (!PARTIAL_MSG || row0 < msgN) {   // block-uniform
            __syncthreads();
            if constexpr (MSG_DOUT == 64) {
                if (tid < 64) sb[tid] = mb1[tid];
                else if (tid < 128) sb[tid] = mb2[tid - 64];
            } else {
                if (tid < 64) sb[tid] = mb1[tid];
                else if (tid < 192) sW2d[tid - 64] = M2[tid - 64];
                else if (tid < 194) sb2d[tid - 192] = mb2[tid - 192];
            }
            #pragma unroll
            for (int j = 0; j < 4; ++j)
                *(float4*)&sXT[c0 + j][r0] =
                    make_float4(ofull[0][j], ofull[1][j], ofull[2][j], ofull[3][j]);
            __syncthreads();

            // GEMM3: H2 = relu(O @ M1 + mb1)  (M1 direct)
            float acc3[4][4] = {};
            #pragma unroll 8
            for (int k = 0; k < 64; ++k) {
                const float4 a = *(const float4*)&sXT[k][r0];
                const float4 w = *(const float4*)&M1[k * 64 + c0];
                MLP_FMA16(acc3, a, w);
            }
            __syncthreads();
            #pragma unroll
            for (int j = 0; j < 4; ++j) {
                const float bj = sb[c0 + j];
                *(float4*)&sXT[c0 + j][r0] = make_float4(
                    fmaxf(acc3[0][j] + bj, 0.f), fmaxf(acc3[1][j] + bj, 0.f),
                    fmaxf(acc3[2][j] + bj, 0.f), fmaxf(acc3[3][j] + bj, 0.f));
            }
            __syncthreads();

            if constexpr (MSG_DOUT == 64) {
                float accM[4][4] = {};
                #pragma unroll 8
                for (int k = 0; k < 64; ++k) {
                    const float4 a = *(const float4*)&sXT[k][r0];
                    const float4 w = *(const float4*)&M2[k * 64 + c0];
                    MLP_FMA16(accM, a, w);
                }
                #pragma unroll
                for (int i = 0; i < 4; ++i) {
                    const int row = row0 + r0 + i;
                    if (row < msgN)
                        *(float4*)&outM[(size_t)row * 64 + c0] =
                            make_float4(accM[i][0] + sb[64 + c0 + 0],
                                        accM[i][1] + sb[64 + c0 + 1],
                                        accM[i][2] + sb[64 + c0 + 2],
                                        accM[i][3] + sb[64 + c0 + 3]);
                }
            } else {
                // decode: 128 threads: (row,col)=(tid>>1, tid&1)
                if (tid < 128) {
                    const int lr = tid >> 1, col = tid & 1;
                    float o0 = sb2d[col], o1 = 0.0f;
                    #pragma unroll 8
                    for (int k = 0; k < 64; k += 2) {
                        o0 = fmaf(sXT[k][lr],     sW2d[k * 2 + col],       o0);
                        o1 = fmaf(sXT[k + 1][lr], sW2d[(k + 1) * 2 + col], o1);
                    }
                    const int row = row0 + lr;
                    if (row < msgN) outM[(size_t)row * 2 + col] = o0 + o1;
                }
            }
        }
    }
}

// plain node-only MLP, same structure (weights direct from global)
template<int DINA, bool HAS_B, bool HAS_SKIP, bool GATHER_A>
__global__ __launch_bounds__(WG)
void mlp2_rt(const float* __restrict__ inA, const int* __restrict__ gidxA,
             const float* __restrict__ inB,
             const float* __restrict__ W1, const float* __restrict__ b1,
             const float* __restrict__ W2, const float* __restrict__ b2,
             const float* __restrict__ skip,
             float* __restrict__ out, int n)
{
    constexpr int XP = 68;
    __shared__ __align__(16) float sXT[64][XP];
    __shared__ float sb[128];

    const int tid = threadIdx.x;
    const int tx = tid & 15, ty = tid >> 4;
    const int c0 = tx * 4, r0 = ty * 4;
    const int row0 = blockIdx.x * 64;
    const int lrow = tid & 63;
    const int kq0 = (tid >> 6) * 4;

    if (tid < 64) sb[tid] = b1[tid];
    else if (tid < 128) sb[tid] = b2[tid - 64];

    {
        const int rg = min(row0 + lrow, n - 1);
        const int ra = GATHER_A ? gidxA[rg] : rg;
        const float* pA = inA + (size_t)ra * DINA;
        #pragma unroll
        for (int kq = kq0; kq < DINA; kq += 16) {
            const float4 v = *(const float4*)(pA + kq);
            sXT[kq + 0][lrow] = v.x; sXT[kq + 1][lrow] = v.y;
            sXT[kq + 2][lrow] = v.z; sXT[kq + 3][lrow] = v.w;
        }
    }
    __syncthreads();

    float acc[4][4] = {};
    #pragma unroll 8
    for (int k = 0; k < DINA; ++k) {
        const float4 a = *(const float4*)&sXT[k][r0];
        const float4 w = *(const float4*)&W1[k * 64 + c0];
        MLP_FMA16(acc, a, w);
    }
    if constexpr (HAS_B) {
        __syncthreads();
        {
            const int rg = min(row0 + lrow, n - 1);
            const float* pB = inB + (size_t)rg * 64;
            #pragma unroll
            for (int kq = kq0; kq < 64; kq += 16) {
                const float4 v = *(const float4*)(pB + kq);
                sXT[kq + 0][lrow] = v.x; sXT[kq + 1][lrow] = v.y;
                sXT[kq + 2][lrow] = v.z; sXT[kq + 3][lrow] = v.w;
            }
        }
        __syncthreads();
        #pragma unroll 8
        for (int k = 0; k < 64; ++k) {
            const float4 a = *(const float4*)&sXT[k][r0];
            const float4 w = *(const float4*)&W1[(DINA + k) * 64 + c0];
            MLP_FMA16(acc, a, w);
        }
    }
    __syncthreads();

    #pragma unroll
    for (int j = 0; j < 4; ++j) {
        const float bj = sb[c0 + j];
        *(float4*)&sXT[c0 + j][r0] = make_float4(
            fmaxf(acc[0][j] + bj, 0.f), fmaxf(acc[1][j] + bj, 0.f),
            fmaxf(acc[2][j] + bj, 0.f), fmaxf(acc[3][j] + bj, 0.f));
    }
    __syncthreads();

    float acc2[4][4] = {};
    #pragma unroll 8
    for (int k = 0; k < 64; ++k) {
        const float4 a = *(const float4*)&sXT[k][r0];
        const float4 w = *(const float4*)&W2[k * 64 + c0];
        MLP_FMA16(acc2, a, w);
    }
    #pragma unroll
    for (int i = 0; i < 4; ++i) {
        const int row = row0 + r0 + i;
        if (row < n) {
            float4 o = make_float4(acc2[i][0] + sb[64 + c0 + 0],
                                   acc2[i][1] + sb[64 + c0 + 1],
                                   acc2[i][2] + sb[64 + c0 + 2],
                                   acc2[i][3] + sb[64 + c0 + 3]);
            if (HAS_SKIP) {
                const float4 s = *(const float4*)&skip[(size_t)row * 64 + c0];
                o.x += s.x; o.y += s.y; o.z += s.z; o.w += s.w;
            }
            *(float4*)&out[(size_t)row * 64 + c0] = o;
        }
    }
}

// ------------- fused XCD-partitioned slot binning (all 4 graphs) -----------
// One dispatch so the 4 graphs' fills overlap (same-stream kernels serialize).
// blockIdx: xcd = blk&7, worker w = blk>>3; w maps to a graph segment.
__global__ __launch_bounds__(WG)
void slot_fill4_xcd_k(const int* __restrict__ s0, const int* __restrict__ r0, int* cu0, int* sl0, int cap0, int E0, int n0,
                      const int* __restrict__ s1, const int* __restrict__ r1, int* cu1, int* sl1, int cap1, int E1, int n1,
                      const int* __restrict__ s2, const int* __restrict__ r2, int* cu2, int* sl2, int cap2, int E2, int n2,
                      const int* __restrict__ s3, const int* __restrict__ r3, int* cu3, int* sl3, int cap3, int E3, int n3,
                      int W0, int W1n, int W2n, int W3n)
{
    const int xcd = blockIdx.x & 7;
    int w = blockIdx.x >> 3;
    const int* s; const int* r; int* cur; int* sl; int cap; int E; int n; int W;
    if (w < W0)              { s=s0; r=r0; cur=cu0; sl=sl0; cap=cap0; E=E0; n=n0; W=W0; }
    else if ((w -= W0) < W1n) { s=s1; r=r1; cur=cu1; sl=sl1; cap=cap1; E=E1; n=n1; W=W1n; }
    else if ((w -= W1n) < W2n){ s=s2; r=r2; cur=cu2; sl=sl2; cap=cap2; E=E2; n=n2; W=W2n; }
    else { w -= W2n;           s=s3; r=r3; cur=cu3; sl=sl3; cap=cap3; E=E3; n=n3; W=W3n; }
    const int lo = (int)(((long)n * xcd) >> 3);
    const int hi = (int)(((long)n * (xcd + 1)) >> 3);
    const int chunk = (E + W - 1) / W;
    const int e0 = w * chunk;
    const int e1 = min(E, e0 + chunk);
    for (int e = e0 + (int)threadIdx.x; e < e1; e += WG) {
        const int v = __builtin_nontemporal_load(&r[e]);
        if (v >= lo && v < hi) {
            const int sv = __builtin_nontemporal_load(&s[e]);
            const int p = atomicAdd(&cur[v], 1);
            if (p < cap) sl[(size_t)v * cap + p] = sv;
        }
    }
}

// ---------------- slot gather-sum (round-12 version) -----------------------
template<bool REMAP>
__global__ __launch_bounds__(WG)
void gather_slots_k(const int* __restrict__ deg, const int* __restrict__ slots,
                    int cap, const int* __restrict__ remap,
                    const float* __restrict__ tab, float* __restrict__ aggr, int n)
{
    const int node = blockIdx.x * (WG / 64) + (threadIdx.x >> 6);
    const int c = threadIdx.x & 63;
    if (node >= n) return;
    const int d = min(deg[node], cap);
    const int* sl = slots + (size_t)node * cap;

    int myidx = 0;
    if (c < d) {
        myidx = __builtin_nontemporal_load(&sl[c]);
        if (REMAP) myidx = remap[myidx];
    }

    float a[8] = {};
    int j = 0;
    for (; j + 7 < d; j += 8) {
        #pragma unroll
        for (int u = 0; u < 8; ++u) {
            const int t = __shfl(myidx, j + u);
            a[u] += tab[(size_t)t * 64 + c];
        }
    }
    #pragma unroll 4
    for (; j < d; ++j) {
        const int t = __shfl(myidx, j);
        a[j & 7] += tab[(size_t)t * 64 + c];
    }
    aggr[(size_t)node * 64 + c] =
        ((a[0] + a[1]) + (a[2] + a[3])) + ((a[4] + a[5]) + (a[6] + a[7]));
}

extern "C" void kernel_launch(void* const* d_in, const int* in_sizes, int n_in,
                              void* d_out, int out_size, void* d_ws, size_t ws_size,
                              hipStream_t stream)
{
    const float* x    = (const float*)d_in[0];
    const float* We1  = (const float*)d_in[1];
    const float* be1  = (const float*)d_in[2];
    const float* We2  = (const float*)d_in[3];
    const float* be2  = (const float*)d_in[4];
    const float* Wm1  = (const float*)d_in[5];
    const float* bm1  = (const float*)d_in[6];
    const float* Wm2  = (const float*)d_in[7];
    const float* bm2  = (const float*)d_in[8];
    const float* Wn1  = (const float*)d_in[9];
    const float* bn1  = (const float*)d_in[10];
    const float* Wn2  = (const float*)d_in[11];
    const float* bn2  = (const float*)d_in[12];
    const float* Wd1  = (const float*)d_in[13];
    const float* bd1  = (const float*)d_in[14];
    const float* Wd2  = (const float*)d_in[15];
    const float* bd2  = (const float*)d_in[16];
    const int* s_fine = (const int*)d_in[17];
    const int* r_fine = (const int*)d_in[18];
    const int* s_ds   = (const int*)d_in[19];
    const int* r_ds   = (const int*)d_in[20];
    const int* s_p    = (const int*)d_in[21];
    const int* r_p    = (const int*)d_in[22];
    const int* s_us   = (const int*)d_in[23];
    const int* r_us   = (const int*)d_in[24];
    const int* uppool   = (const int*)d_in[25];
    const int* downpool = (const int*)d_in[26];

    const int N   = in_sizes[0] / 16;
    const int E   = in_sizes[17];
    const int EDS = in_sizes[19];
    const int EP  = in_sizes[21];
    const int EUS = in_sizes[23];
    const int NP  = in_sizes[26];

    const int CAP_FINE = 48, CAP_DS = 32, CAP_PP = 48, CAP_US = 32;

    // ---- workspace ----
    float* B0  = (float*)d_ws;
    float* B1  = B0 + (size_t)N * 64;
    float* B2  = B1 + (size_t)N * 64;
    float* B3  = B2 + (size_t)N * 64;
    float* HPa = B3 + (size_t)N * 64;
    float* HPb = HPa + (size_t)NP * 64;
    int* ip = (int*)(HPb + (size_t)NP * 64);
    auto alloc_i = [&](size_t n) { int* p = ip; ip += n; return p; };
    int* cur_fine = alloc_i(N);
    int* cur_ds   = alloc_i(N);
    int* cur_pp   = alloc_i(NP);
    int* cur_us   = alloc_i(NP);
    int* sl_fine  = alloc_i((size_t)N * CAP_FINE);
    int* sl_ds    = alloc_i((size_t)N * CAP_DS);
    int* sl_pp    = alloc_i((size_t)NP * CAP_PP);
    int* sl_us    = alloc_i((size_t)NP * CAP_US);

    const int gN  = (N + 63) / 64;
    const int gNP = (NP + 63) / 64;
    const int gaN  = (N + 3) / 4;
    const int gaNP = (NP + 3) / 4;

    // ---- fills: one fused XCD-partitioned dispatch (4 graphs overlap)
    hipMemsetAsync(cur_fine, 0, (size_t)(2 * N + 2 * NP) * sizeof(int), stream);
    {
        const int W0 = 256, W1n = 128, W2n = 64, W3n = 64;   // workers per graph
        slot_fill4_xcd_k<<<8 * (W0 + W1n + W2n + W3n), WG, 0, stream>>>(
            s_fine, r_fine, cur_fine, sl_fine, CAP_FINE, E,   N,
            s_ds,   r_ds,   cur_ds,   sl_ds,   CAP_DS,   EDS, N,
            s_p,    r_p,    cur_pp,   sl_pp,   CAP_PP,   EP,  NP,
            s_us,   r_us,   cur_us,   sl_us,   CAP_US,   EUS, NP,
            W0, W1n, W2n, W3n);
    }

    // ---- F_enc: encode + msg0 -> h0=B0, msg0=B1
    mlp2_fused<16,false,false,false,64,false,true><<<gN,WG,0,stream>>>(
        x,nullptr,nullptr, We1,be1,We2,be2, nullptr,B0,
        Wm1+0*4096,bm1+0*64,Wm2+0*4096,bm2+0*64, B1, N, N);
    gather_slots_k<false><<<gaN,WG,0,stream>>>(cur_fine,sl_fine,CAP_FINE,nullptr,B1,B2,N);

    // ---- F_n0m1: node0(h0,B2) -> h1=B3 ; msg1=B0
    mlp2_fused<64,true,false,false,64,false,true><<<gN,WG,0,stream>>>(
        B0,nullptr,B2, Wn1+0*8192,bn1+0*64,Wn2+0*4096,bn2+0*64, nullptr,B3,
        Wm1+1*4096,bm1+1*64,Wm2+1*4096,bm2+1*64, B0, N, N);
    gather_slots_k<false><<<gaN,WG,0,stream>>>(cur_fine,sl_fine,CAP_FINE,nullptr,B0,B2,N);

    // ---- F_n1m2: node1(h1,B2) -> h2=B1 (skip) ; msg2=B0 rows<NP
    mlp2_fused<64,true,false,false,64,true,true><<<gN,WG,0,stream>>>(
        B3,nullptr,B2, Wn1+1*8192,bn1+1*64,Wn2+1*4096,bn2+1*64, nullptr,B1,
        Wm1+2*4096,bm1+2*64,Wm2+2*4096,bm2+2*64, B0, NP, N);
    gather_slots_k<true><<<gaN,WG,0,stream>>>(cur_ds,sl_ds,CAP_DS,uppool,B0,B2,N);

    // ---- N2: node2 (h2[uppool], B2) -> g=B3
    mlp2_rt<64,true,false,true><<<gN,WG,0,stream>>>(
        B1,uppool,B2, Wn1+2*8192,bn1+2*64,Wn2+2*4096,bn2+2*64, nullptr,B3,N);

    // ---- M3: msg3 over g[downpool] -> HPa
    mlp2_rt<64,false,false,true><<<gNP,WG,0,stream>>>(
        B3,downpool,nullptr, Wm1+3*4096,bm1+3*64,Wm2+3*4096,bm2+3*64, nullptr,HPa,NP);
    gather_slots_k<false><<<gaNP,WG,0,stream>>>(cur_pp,sl_pp,CAP_PP,nullptr,HPa,B2,NP);

    // ---- F_n3m4: node3(g[downpool],B2) -> hp1=HPb ; msg4=HPa
    mlp2_fused<64,true,false,true,64,false,true><<<gNP,WG,0,stream>>>(
        B3,downpool,B2, Wn1+3*8192,bn1+3*64,Wn2+3*4096,bn2+3*64, nullptr,HPb,
        Wm1+4*4096,bm1+4*64,Wm2+4*4096,bm2+4*64, HPa, NP, NP);
    gather_slots_k<false><<<gaNP,WG,0,stream>>>(cur_pp,sl_pp,CAP_PP,nullptr,HPa,B2,NP);

    // ---- F_n4m5: node4(hp1,B2) -> hp2=HPa ; msg5=HPb (same-row overwrite, safe)
    mlp2_fused<64,true,false,false,64,false,true><<<gNP,WG,0,stream>>>(
        HPb,nullptr,B2, Wn1+4*8192,bn1+4*64,Wn2+4*4096,bn2+4*64, nullptr,HPa,
        Wm1+5*4096,bm1+5*64,Wm2+5*4096,bm2+5*64, HPb, NP, NP);
    gather_slots_k<true><<<gaNP,WG,0,stream>>>(cur_us,sl_us,CAP_US,downpool,HPb,B2,NP);

    // ---- F_n5m6: node5(hp2[downpool],B2) -> g'=HPb ; msg6=B3 (rows<NP)
    mlp2_fused<64,true,false,true,64,false,true><<<gNP,WG,0,stream>>>(
        HPa,downpool,B2, Wn1+5*8192,bn1+5*64,Wn2+5*4096,bn2+5*64, nullptr,HPb,
        Wm1+6*4096,bm1+6*64,Wm2+6*4096,bm2+6*64, B3, NP, NP);
    gather_slots_k<true><<<gaN,WG,0,stream>>>(cur_fine,sl_fine,CAP_FINE,uppool,B3,B2,N);

    // ---- F_n6m7: node6(g'[uppool],B2,+skip B1) -> h7=B0 ; msg7=B3
    mlp2_fused<64,true,true,true,64,false,true><<<gN,WG,0,stream>>>(
        HPb,uppool,B2, Wn1+6*8192,bn1+6*64,Wn2+6*4096,bn2+6*64, B1,B0,
        Wm1+7*4096,bm1+7*64,Wm2+7*4096,bm2+7*64, B3, N, N);
    gather_slots_k<false><<<gaN,WG,0,stream>>>(cur_fine,sl_fine,CAP_FINE,nullptr,B3,B2,N);

    // ---- F_n7dec: node7(h7,B2,+skip B1) -> (no out1) ; decode -> d_out
    mlp2_fused<64,true,true,false,2,false,false><<<gN,WG,0,stream>>>(
        B0,nullptr,B2, Wn1+7*8192,bn1+7*64,Wn2+7*4096,bn2+7*64, B1,nullptr,
        Wd1,bd1,Wd2,bd2, (float*)d_out, N, N);
}

// Round 16
// 1055.738 us; speedup vs baseline: 1.1697x; 1.0428x over previous
//
#include <hip/hip_runtime.h>

#define WG 256

#define MLP_FMA16(ACC, A, W) do { \
    ACC[0][0]=fmaf(A.x,W.x,ACC[0][0]); ACC[0][1]=fmaf(A.x,W.y,ACC[0][1]); \
    ACC[0][2]=fmaf(A.x,W.z,ACC[0][2]); ACC[0][3]=fmaf(A.x,W.w,ACC[0][3]); \
    ACC[1][0]=fmaf(A.y,W.x,ACC[1][0]); ACC[1][1]=fmaf(A.y,W.y,ACC[1][1]); \
    ACC[1][2]=fmaf(A.y,W.z,ACC[1][2]); ACC[1][3]=fmaf(A.y,W.w,ACC[1][3]); \
    ACC[2][0]=fmaf(A.z,W.x,ACC[2][0]); ACC[2][1]=fmaf(A.z,W.y,ACC[2][1]); \
    ACC[2][2]=fmaf(A.z,W.z,ACC[2][2]); ACC[2][3]=fmaf(A.z,W.w,ACC[2][3]); \
    ACC[3][0]=fmaf(A.w,W.x,ACC[3][0]); ACC[3][1]=fmaf(A.w,W.y,ACC[3][1]); \
    ACC[3][2]=fmaf(A.w,W.z,ACC[3][2]); ACC[3][3]=fmaf(A.w,W.w,ACC[3][3]); \
} while (0)

// =============== fused: node-MLP (+out1) then msg-MLP of next layer =========
// Round-12 champion structure: 64-row blocks, 256 thr, 4x4 acc, LDS weights,
// sXT capped at 64 rows (concat input as two K-phases). ~34.8 KB -> 4 blk/CU.
template<int DINA, bool HAS_B, bool HAS_SKIP, bool GATHER_A,
         int MSG_DOUT, bool PARTIAL_MSG, bool WRITE_OUT1>
__global__ __launch_bounds__(WG)
void mlp2_fused(const float* __restrict__ inA, const int* __restrict__ gidxA,
                const float* __restrict__ inB,
                const float* __restrict__ W1, const float* __restrict__ b1,
                const float* __restrict__ W2, const float* __restrict__ b2,
                const float* __restrict__ skip, float* __restrict__ out1,
                const float* __restrict__ M1, const float* __restrict__ mb1,
                const float* __restrict__ M2, const float* __restrict__ mb2,
                float* __restrict__ outM, int msgN, int n)
{
    constexpr int XP = 68;                           // b128-aligned, conflict-free
    __shared__ __align__(16) float sXT[64][XP];      // X^T phases / H^T / O^T / H2^T
    __shared__ __align__(16) float sW[64 * 64];      // W1 phases / W2 / M1 / M2
    __shared__ float sb[128];
    __shared__ float sW2d[128];                      // decode W2 (64x2)
    __shared__ float sb2d[2];

    const int tid = threadIdx.x;
    const int tx = tid & 15, ty = tid >> 4;
    const int c0 = tx * 4, r0 = ty * 4;
    const int row0 = blockIdx.x * 64;
    const int lrow = tid & 63;
    const int kq0 = (tid >> 6) * 4;

    // ---- stage W1 phase A (DINA rows), biases
    for (int i = tid * 4; i < DINA * 64; i += WG * 4)
        *(float4*)&sW[i] = *(const float4*)&W1[i];
    if (tid < 64) sb[tid] = b1[tid];
    else if (tid < 128) sb[tid] = b2[tid - 64];

    // ---- stage X^T phase A (lane = row, conflict-free)
    {
        const int rg = min(row0 + lrow, n - 1);
        const int ra = GATHER_A ? gidxA[rg] : rg;
        const float* pA = inA + (size_t)ra * DINA;
        #pragma unroll
        for (int kq = kq0; kq < DINA; kq += 16) {
            const float4 v = *(const float4*)(pA + kq);
            sXT[kq + 0][lrow] = v.x; sXT[kq + 1][lrow] = v.y;
            sXT[kq + 2][lrow] = v.z; sXT[kq + 3][lrow] = v.w;
        }
    }
    __syncthreads();

    // ---- GEMM1 phase A
    float acc[4][4] = {};
    #pragma unroll 8
    for (int k = 0; k < DINA; ++k) {
        const float4 a = *(const float4*)&sXT[k][r0];
        const float4 w = *(const float4*)&sW[k * 64 + c0];
        MLP_FMA16(acc, a, w);
    }

    // ---- GEMM1 phase B: inB against W1 rows DINA..DINA+63
    if constexpr (HAS_B) {
        __syncthreads();
        for (int i = tid * 4; i < 64 * 64; i += WG * 4)
            *(float4*)&sW[i] = *(const float4*)&W1[DINA * 64 + i];
        {
            const int rg = min(row0 + lrow, n - 1);
            const float* pB = inB + (size_t)rg * 64;
            #pragma unroll
            for (int kq = kq0; kq < 64; kq += 16) {
                const float4 v = *(const float4*)(pB + kq);
                sXT[kq + 0][lrow] = v.x; sXT[kq + 1][lrow] = v.y;
                sXT[kq + 2][lrow] = v.z; sXT[kq + 3][lrow] = v.w;
            }
        }
        __syncthreads();
        #pragma unroll 8
        for (int k = 0; k < 64; ++k) {
            const float4 a = *(const float4*)&sXT[k][r0];
            const float4 w = *(const float4*)&sW[k * 64 + c0];
            MLP_FMA16(acc, a, w);
        }
    }
    __syncthreads();

    // ---- stage W2; write H^T
    for (int i = tid * 4; i < 64 * 64; i += WG * 4)
        *(float4*)&sW[i] = *(const float4*)&W2[i];
    #pragma unroll
    for (int j = 0; j < 4; ++j) {
        const float bj = sb[c0 + j];
        *(float4*)&sXT[c0 + j][r0] = make_float4(
            fmaxf(acc[0][j] + bj, 0.f), fmaxf(acc[1][j] + bj, 0.f),
            fmaxf(acc[2][j] + bj, 0.f), fmaxf(acc[3][j] + bj, 0.f));
    }
    __syncthreads();

    // ---- GEMM2
    float acc2[4][4] = {};
    #pragma unroll 8
    for (int k = 0; k < 64; ++k) {
        const float4 a = *(const float4*)&sXT[k][r0];
        const float4 w = *(const float4*)&sW[k * 64 + c0];
        MLP_FMA16(acc2, a, w);
    }

    // ---- O = acc2 + b2 (+skip); write out1
    float ofull[4][4];
    #pragma unroll
    for (int i = 0; i < 4; ++i) {
        const int row = row0 + r0 + i;
        float4 s = make_float4(0.f, 0.f, 0.f, 0.f);
        if (HAS_SKIP && row < n) s = *(const float4*)&skip[(size_t)row * 64 + c0];
        ofull[i][0] = acc2[i][0] + sb[64 + c0 + 0] + s.x;
        ofull[i][1] = acc2[i][1] + sb[64 + c0 + 1] + s.y;
        ofull[i][2] = acc2[i][2] + sb[64 + c0 + 2] + s.z;
        ofull[i][3] = acc2[i][3] + sb[64 + c0 + 3] + s.w;
        if (WRITE_OUT1 && row < n)
            *(float4*)&out1[(size_t)row * 64 + c0] =
                make_float4(ofull[i][0], ofull[i][1], ofull[i][2], ofull[i][3]);
    }

    // ================= msg tail =================
    if constexpr (MSG_DOUT > 0) {
        if (!PARTIAL_MSG || row0 < msgN) {   // block-uniform
            __syncthreads();
            for (int i = tid * 4; i < 64 * 64; i += WG * 4)
                *(float4*)&sW[i] = *(const float4*)&M1[i];
            if constexpr (MSG_DOUT == 64) {
                if (tid < 64) sb[tid] = mb1[tid];
                else if (tid < 128) sb[tid] = mb2[tid - 64];
            } else {
                if (tid < 64) sb[tid] = mb1[tid];
                else if (tid < 192) sW2d[tid - 64] = M2[tid - 64];
                else if (tid < 194) sb2d[tid - 192] = mb2[tid - 192];
            }
            #pragma unroll
            for (int j = 0; j < 4; ++j)
                *(float4*)&sXT[c0 + j][r0] =
                    make_float4(ofull[0][j], ofull[1][j], ofull[2][j], ofull[3][j]);
            __syncthreads();

            // GEMM3: H2 = relu(O @ M1 + mb1)
            float acc3[4][4] = {};
            #pragma unroll 8
            for (int k = 0; k < 64; ++k) {
                const float4 a = *(const float4*)&sXT[k][r0];
                const float4 w = *(const float4*)&sW[k * 64 + c0];
                MLP_FMA16(acc3, a, w);
            }
            __syncthreads();
            if constexpr (MSG_DOUT == 64) {
                for (int i = tid * 4; i < 64 * 64; i += WG * 4)
                    *(float4*)&sW[i] = *(const float4*)&M2[i];
            }
            #pragma unroll
            for (int j = 0; j < 4; ++j) {
                const float bj = sb[c0 + j];
                *(float4*)&sXT[c0 + j][r0] = make_float4(
                    fmaxf(acc3[0][j] + bj, 0.f), fmaxf(acc3[1][j] + bj, 0.f),
                    fmaxf(acc3[2][j] + bj, 0.f), fmaxf(acc3[3][j] + bj, 0.f));
            }
            __syncthreads();

            if constexpr (MSG_DOUT == 64) {
                float accM[4][4] = {};
                #pragma unroll 8
                for (int k = 0; k < 64; ++k) {
                    const float4 a = *(const float4*)&sXT[k][r0];
                    const float4 w = *(const float4*)&sW[k * 64 + c0];
                    MLP_FMA16(accM, a, w);
                }
                #pragma unroll
                for (int i = 0; i < 4; ++i) {
                    const int row = row0 + r0 + i;
                    if (row < msgN)
                        *(float4*)&outM[(size_t)row * 64 + c0] =
                            make_float4(accM[i][0] + sb[64 + c0 + 0],
                                        accM[i][1] + sb[64 + c0 + 1],
                                        accM[i][2] + sb[64 + c0 + 2],
                                        accM[i][3] + sb[64 + c0 + 3]);
                }
            } else {
                // decode: 128 threads: (row,col)=(tid>>1, tid&1)
                if (tid < 128) {
                    const int lr = tid >> 1, col = tid & 1;
                    float o0 = sb2d[col], o1 = 0.0f;
                    #pragma unroll 8
                    for (int k = 0; k < 64; k += 2) {
                        o0 = fmaf(sXT[k][lr],     sW2d[k * 2 + col],       o0);
                        o1 = fmaf(sXT[k + 1][lr], sW2d[(k + 1) * 2 + col], o1);
                    }
                    const int row = row0 + lr;
                    if (row < msgN) outM[(size_t)row * 2 + col] = o0 + o1;
                }
            }
        }
    }
}

// plain node-only MLP, round-12 structure
template<int DINA, bool HAS_B, bool HAS_SKIP, bool GATHER_A>
__global__ __launch_bounds__(WG)
void mlp2_rt(const float* __restrict__ inA, const int* __restrict__ gidxA,
             const float* __restrict__ inB,
             const float* __restrict__ W1, const float* __restrict__ b1,
             const float* __restrict__ W2, const float* __restrict__ b2,
             const float* __restrict__ skip,
             float* __restrict__ out, int n)
{
    constexpr int XP = 68;
    __shared__ __align__(16) float sXT[64][XP];
    __shared__ __align__(16) float sW[64 * 64];
    __shared__ float sb[128];

    const int tid = threadIdx.x;
    const int tx = tid & 15, ty = tid >> 4;
    const int c0 = tx * 4, r0 = ty * 4;
    const int row0 = blockIdx.x * 64;
    const int lrow = tid & 63;
    const int kq0 = (tid >> 6) * 4;

    for (int i = tid * 4; i < DINA * 64; i += WG * 4)
        *(float4*)&sW[i] = *(const float4*)&W1[i];
    if (tid < 64) sb[tid] = b1[tid];
    else if (tid < 128) sb[tid] = b2[tid - 64];

    {
        const int rg = min(row0 + lrow, n - 1);
        const int ra = GATHER_A ? gidxA[rg] : rg;
        const float* pA = inA + (size_t)ra * DINA;
        #pragma unroll
        for (int kq = kq0; kq < DINA; kq += 16) {
            const float4 v = *(const float4*)(pA + kq);
            sXT[kq + 0][lrow] = v.x; sXT[kq + 1][lrow] = v.y;
            sXT[kq + 2][lrow] = v.z; sXT[kq + 3][lrow] = v.w;
        }
    }
    __syncthreads();

    float acc[4][4] = {};
    #pragma unroll 8
    for (int k = 0; k < DINA; ++k) {
        const float4 a = *(const float4*)&sXT[k][r0];
        const float4 w = *(const float4*)&sW[k * 64 + c0];
        MLP_FMA16(acc, a, w);
    }
    if constexpr (HAS_B) {
        __syncthreads();
        for (int i = tid * 4; i < 64 * 64; i += WG * 4)
            *(float4*)&sW[i] = *(const float4*)&W1[DINA * 64 + i];
        {
            const int rg = min(row0 + lrow, n - 1);
            const float* pB = inB + (size_t)rg * 64;
            #pragma unroll
            for (int kq = kq0; kq < 64; kq += 16) {
                const float4 v = *(const float4*)(pB + kq);
                sXT[kq + 0][lrow] = v.x; sXT[kq + 1][lrow] = v.y;
                sXT[kq + 2][lrow] = v.z; sXT[kq + 3][lrow] = v.w;
            }
        }
        __syncthreads();
        #pragma unroll 8
        for (int k = 0; k < 64; ++k) {
            const float4 a = *(const float4*)&sXT[k][r0];
            const float4 w = *(const float4*)&sW[k * 64 + c0];
            MLP_FMA16(acc, a, w);
        }
    }
    __syncthreads();

    for (int i = tid * 4; i < 64 * 64; i += WG * 4)
        *(float4*)&sW[i] = *(const float4*)&W2[i];
    #pragma unroll
    for (int j = 0; j < 4; ++j) {
        const float bj = sb[c0 + j];
        *(float4*)&sXT[c0 + j][r0] = make_float4(
            fmaxf(acc[0][j] + bj, 0.f), fmaxf(acc[1][j] + bj, 0.f),
            fmaxf(acc[2][j] + bj, 0.f), fmaxf(acc[3][j] + bj, 0.f));
    }
    __syncthreads();

    float acc2[4][4] = {};
    #pragma unroll 8
    for (int k = 0; k < 64; ++k) {
        const float4 a = *(const float4*)&sXT[k][r0];
        const float4 w = *(const float4*)&sW[k * 64 + c0];
        MLP_FMA16(acc2, a, w);
    }
    #pragma unroll
    for (int i = 0; i < 4; ++i) {
        const int row = row0 + r0 + i;
        if (row < n) {
            float4 o = make_float4(acc2[i][0] + sb[64 + c0 + 0],
                                   acc2[i][1] + sb[64 + c0 + 1],
                                   acc2[i][2] + sb[64 + c0 + 2],
                                   acc2[i][3] + sb[64 + c0 + 3]);
            if (HAS_SKIP) {
                const float4 s = *(const float4*)&skip[(size_t)row * 64 + c0];
                o.x += s.x; o.y += s.y; o.z += s.z; o.w += s.w;
            }
            *(float4*)&out[(size_t)row * 64 + c0] = o;
        }
    }
}

// ===== combo dispatch: 4 XCD-partitioned fills UNION encode+msg0 MLP ========
// Blocks [0,FILLB): fill logic (0 LDS used). Blocks [FILLB,..): encode MLP
// (weights read from global -> 18.4 KB LDS -> doesn't cap fill occupancy:
// 8 blocks/CU = the 2048-thread cap anyway). Fill and encode are independent
// (fill writes slots/cursors; encode reads x/weights, writes B0/B1) so they
// truly overlap inside one dispatch -> encode hides in the fill's shadow.
__global__ __launch_bounds__(WG)
void fill4_enc_k(const int* __restrict__ s0, const int* __restrict__ r0v, int* cu0, int* sl0, int cap0, int E0, int n0,
                 const int* __restrict__ s1, const int* __restrict__ r1, int* cu1, int* sl1, int cap1, int E1, int n1,
                 const int* __restrict__ s2, const int* __restrict__ r2, int* cu2, int* sl2, int cap2, int E2, int n2,
                 const int* __restrict__ s3, const int* __restrict__ r3, int* cu3, int* sl3, int cap3, int E3, int n3,
                 int W0, int W1n, int W2n, int W3n, int FILLB,
                 const float* __restrict__ x,
                 const float* __restrict__ We1, const float* __restrict__ be1,
                 const float* __restrict__ We2, const float* __restrict__ be2,
                 float* __restrict__ h0,
                 const float* __restrict__ M1, const float* __restrict__ mb1,
                 const float* __restrict__ M2, const float* __restrict__ mb2,
                 float* __restrict__ msg0, int N)
{
    constexpr int XP = 68;
    __shared__ __align__(16) float sXT[64][XP];
    __shared__ float sb[128];

    if ((int)blockIdx.x < FILLB) {
        // ---------------- fill role ----------------
        const int xcd = blockIdx.x & 7;
        int w = blockIdx.x >> 3;
        const int* s; const int* r; int* cur; int* sl; int cap; int E; int n; int W;
        if (w < W0)               { s=s0; r=r0v; cur=cu0; sl=sl0; cap=cap0; E=E0; n=n0; W=W0; }
        else if ((w -= W0) < W1n) { s=s1; r=r1;  cur=cu1; sl=sl1; cap=cap1; E=E1; n=n1; W=W1n; }
        else if ((w -= W1n) < W2n){ s=s2; r=r2;  cur=cu2; sl=sl2; cap=cap2; E=E2; n=n2; W=W2n; }
        else { w -= W2n;            s=s3; r=r3;  cur=cu3; sl=sl3; cap=cap3; E=E3; n=n3; W=W3n; }
        const int lo = (int)(((long)n * xcd) >> 3);
        const int hi = (int)(((long)n * (xcd + 1)) >> 3);
        const int chunk = (E + W - 1) / W;
        const int e0 = w * chunk;
        const int e1 = min(E, e0 + chunk);
        for (int e = e0 + (int)threadIdx.x; e < e1; e += WG) {
            const int v = __builtin_nontemporal_load(&r[e]);
            if (v >= lo && v < hi) {
                const int sv = __builtin_nontemporal_load(&s[e]);
                const int p = atomicAdd(&cur[v], 1);
                if (p < cap) sl[(size_t)v * cap + p] = sv;
            }
        }
        return;
    }

    // ---------------- encode role: h0 = MLP2(x); msg0 = MLP2(h0) ----------------
    const int bid = blockIdx.x - FILLB;
    const int tid = threadIdx.x;
    const int tx = tid & 15, ty = tid >> 4;
    const int c0 = tx * 4, r0 = ty * 4;
    const int row0 = bid * 64;
    const int lrow = tid & 63;
    const int kq0 = (tid >> 6) * 4;

    if (tid < 64) sb[tid] = be1[tid];
    else if (tid < 128) sb[tid] = be2[tid - 64];

    // stage X^T (DINA=16): wave w covers k = w*4..w*4+3
    {
        const int rg = min(row0 + lrow, N - 1);
        const float* pA = x + (size_t)rg * 16;
        const float4 v = *(const float4*)(pA + kq0);
        sXT[kq0 + 0][lrow] = v.x; sXT[kq0 + 1][lrow] = v.y;
        sXT[kq0 + 2][lrow] = v.z; sXT[kq0 + 3][lrow] = v.w;
    }
    __syncthreads();

    // GEMM1 (We1 from global, 16x64)
    float acc[4][4] = {};
    #pragma unroll
    for (int k = 0; k < 16; ++k) {
        const float4 a = *(const float4*)&sXT[k][r0];
        const float4 w = *(const float4*)&We1[k * 64 + c0];
        MLP_FMA16(acc, a, w);
    }
    __syncthreads();
    #pragma unroll
    for (int j = 0; j < 4; ++j) {
        const float bj = sb[c0 + j];
        *(float4*)&sXT[c0 + j][r0] = make_float4(
            fmaxf(acc[0][j] + bj, 0.f), fmaxf(acc[1][j] + bj, 0.f),
            fmaxf(acc[2][j] + bj, 0.f), fmaxf(acc[3][j] + bj, 0.f));
    }
    __syncthreads();

    // GEMM2 (We2 from global)
    float acc2[4][4] = {};
    #pragma unroll 8
    for (int k = 0; k < 64; ++k) {
        const float4 a = *(const float4*)&sXT[k][r0];
        const float4 w = *(const float4*)&We2[k * 64 + c0];
        MLP_FMA16(acc2, a, w);
    }
    float ofull[4][4];
    #pragma unroll
    for (int i = 0; i < 4; ++i) {
        const int row = row0 + r0 + i;
        ofull[i][0] = acc2[i][0] + sb[64 + c0 + 0];
        ofull[i][1] = acc2[i][1] + sb[64 + c0 + 1];
        ofull[i][2] = acc2[i][2] + sb[64 + c0 + 2];
        ofull[i][3] = acc2[i][3] + sb[64 + c0 + 3];
        if (row < N)
            *(float4*)&h0[(size_t)row * 64 + c0] =
                make_float4(ofull[i][0], ofull[i][1], ofull[i][2], ofull[i][3]);
    }

    // msg tail: msg0 = relu(h0 @ M1 + mb1) @ M2 + mb2
    __syncthreads();
    if (tid < 64) sb[tid] = mb1[tid];
    else if (tid < 128) sb[tid] = mb2[tid - 64];
    #pragma unroll
    for (int j = 0; j < 4; ++j)
        *(float4*)&sXT[c0 + j][r0] =
            make_float4(ofull[0][j], ofull[1][j], ofull[2][j], ofull[3][j]);
    __syncthreads();

    float acc3[4][4] = {};
    #pragma unroll 8
    for (int k = 0; k < 64; ++k) {
        const float4 a = *(const float4*)&sXT[k][r0];
        const float4 w = *(const float4*)&M1[k * 64 + c0];
        MLP_FMA16(acc3, a, w);
    }
    __syncthreads();
    #pragma unroll
    for (int j = 0; j < 4; ++j) {
        const float bj = sb[c0 + j];
        *(float4*)&sXT[c0 + j][r0] = make_float4(
            fmaxf(acc3[0][j] + bj, 0.f), fmaxf(acc3[1][j] + bj, 0.f),
            fmaxf(acc3[2][j] + bj, 0.f), fmaxf(acc3[3][j] + bj, 0.f));
    }
    __syncthreads();

    float accM[4][4] = {};
    #pragma unroll 8
    for (int k = 0; k < 64; ++k) {
        const float4 a = *(const float4*)&sXT[k][r0];
        const float4 w = *(const float4*)&M2[k * 64 + c0];
        MLP_FMA16(accM, a, w);
    }
    #pragma unroll
    for (int i = 0; i < 4; ++i) {
        const int row = row0 + r0 + i;
        if (row < N)
            *(float4*)&msg0[(size_t)row * 64 + c0] =
                make_float4(accM[i][0] + sb[64 + c0 + 0],
                            accM[i][1] + sb[64 + c0 + 1],
                            accM[i][2] + sb[64 + c0 + 2],
                            accM[i][3] + sb[64 + c0 + 3]);
    }
}

// ---------------- slot gather-sum (round-12 version) -----------------------
template<bool REMAP>
__global__ __launch_bounds__(WG)
void gather_slots_k(const int* __restrict__ deg, const int* __restrict__ slots,
                    int cap, const int* __restrict__ remap,
                    const float* __restrict__ tab, float* __restrict__ aggr, int n)
{
    const int node = blockIdx.x * (WG / 64) + (threadIdx.x >> 6);
    const int c = threadIdx.x & 63;
    if (node >= n) return;
    const int d = min(deg[node], cap);
    const int* sl = slots + (size_t)node * cap;

    int myidx = 0;
    if (c < d) {
        myidx = __builtin_nontemporal_load(&sl[c]);
        if (REMAP) myidx = remap[myidx];
    }

    float a[8] = {};
    int j = 0;
    for (; j + 7 < d; j += 8) {
        #pragma unroll
        for (int u = 0; u < 8; ++u) {
            const int t = __shfl(myidx, j + u);
            a[u] += tab[(size_t)t * 64 + c];
        }
    }
    #pragma unroll 4
    for (; j < d; ++j) {
        const int t = __shfl(myidx, j);
        a[j & 7] += tab[(size_t)t * 64 + c];
    }
    aggr[(size_t)node * 64 + c] =
        ((a[0] + a[1]) + (a[2] + a[3])) + ((a[4] + a[5]) + (a[6] + a[7]));
}

extern "C" void kernel_launch(void* const* d_in, const int* in_sizes, int n_in,
                              void* d_out, int out_size, void* d_ws, size_t ws_size,
                              hipStream_t stream)
{
    const float* x    = (const float*)d_in[0];
    const float* We1  = (const float*)d_in[1];
    const float* be1  = (const float*)d_in[2];
    const float* We2  = (const float*)d_in[3];
    const float* be2  = (const float*)d_in[4];
    const float* Wm1  = (const float*)d_in[5];
    const float* bm1  = (const float*)d_in[6];
    const float* Wm2  = (const float*)d_in[7];
    const float* bm2  = (const float*)d_in[8];
    const float* Wn1  = (const float*)d_in[9];
    const float* bn1  = (const float*)d_in[10];
    const float* Wn2  = (const float*)d_in[11];
    const float* bn2  = (const float*)d_in[12];
    const float* Wd1  = (const float*)d_in[13];
    const float* bd1  = (const float*)d_in[14];
    const float* Wd2  = (const float*)d_in[15];
    const float* bd2  = (const float*)d_in[16];
    const int* s_fine = (const int*)d_in[17];
    const int* r_fine = (const int*)d_in[18];
    const int* s_ds   = (const int*)d_in[19];
    const int* r_ds   = (const int*)d_in[20];
    const int* s_p    = (const int*)d_in[21];
    const int* r_p    = (const int*)d_in[22];
    const int* s_us   = (const int*)d_in[23];
    const int* r_us   = (const int*)d_in[24];
    const int* uppool   = (const int*)d_in[25];
    const int* downpool = (const int*)d_in[26];

    const int N   = in_sizes[0] / 16;
    const int E   = in_sizes[17];
    const int EDS = in_sizes[19];
    const int EP  = in_sizes[21];
    const int EUS = in_sizes[23];
    const int NP  = in_sizes[26];

    const int CAP_FINE = 48, CAP_DS = 32, CAP_PP = 48, CAP_US = 32;

    // ---- workspace ----
    float* B0  = (float*)d_ws;
    float* B1  = B0 + (size_t)N * 64;
    float* B2  = B1 + (size_t)N * 64;
    float* B3  = B2 + (size_t)N * 64;
    float* HPa = B3 + (size_t)N * 64;
    float* HPb = HPa + (size_t)NP * 64;
    int* ip = (int*)(HPb + (size_t)NP * 64);
    auto alloc_i = [&](size_t n) { int* p = ip; ip += n; return p; };
    int* cur_fine = alloc_i(N);
    int* cur_ds   = alloc_i(N);
    int* cur_pp   = alloc_i(NP);
    int* cur_us   = alloc_i(NP);
    int* sl_fine  = alloc_i((size_t)N * CAP_FINE);
    int* sl_ds    = alloc_i((size_t)N * CAP_DS);
    int* sl_pp    = alloc_i((size_t)NP * CAP_PP);
    int* sl_us    = alloc_i((size_t)NP * CAP_US);

    const int gN  = (N + 63) / 64;
    const int gNP = (NP + 63) / 64;
    const int gaN  = (N + 3) / 4;
    const int gaNP = (NP + 3) / 4;

    // ---- fills + encode in one dispatch
    hipMemsetAsync(cur_fine, 0, (size_t)(2 * N + 2 * NP) * sizeof(int), stream);
    {
        const int W0 = 256, W1n = 128, W2n = 64, W3n = 64;
        const int FILLB = 8 * (W0 + W1n + W2n + W3n);   // 4096
        fill4_enc_k<<<FILLB + gN, WG, 0, stream>>>(
            s_fine, r_fine, cur_fine, sl_fine, CAP_FINE, E,   N,
            s_ds,   r_ds,   cur_ds,   sl_ds,   CAP_DS,   EDS, N,
            s_p,    r_p,    cur_pp,   sl_pp,   CAP_PP,   EP,  NP,
            s_us,   r_us,   cur_us,   sl_us,   CAP_US,   EUS, NP,
            W0, W1n, W2n, W3n, FILLB,
            x, We1, be1, We2, be2, B0,
            Wm1 + 0*4096, bm1 + 0*64, Wm2 + 0*4096, bm2 + 0*64, B1, N);
    }
    gather_slots_k<false><<<gaN,WG,0,stream>>>(cur_fine,sl_fine,CAP_FINE,nullptr,B1,B2,N);

    // ---- F_n0m1: node0(h0,B2) -> h1=B3 ; msg1=B0
    mlp2_fused<64,true,false,false,64,false,true><<<gN,WG,0,stream>>>(
        B0,nullptr,B2, Wn1+0*8192,bn1+0*64,Wn2+0*4096,bn2+0*64, nullptr,B3,
        Wm1+1*4096,bm1+1*64,Wm2+1*4096,bm2+1*64, B0, N, N);
    gather_slots_k<false><<<gaN,WG,0,stream>>>(cur_fine,sl_fine,CAP_FINE,nullptr,B0,B2,N);

    // ---- F_n1m2: node1(h1,B2) -> h2=B1 (skip) ; msg2=B0 rows<NP
    mlp2_fused<64,true,false,false,64,true,true><<<gN,WG,0,stream>>>(
        B3,nullptr,B2, Wn1+1*8192,bn1+1*64,Wn2+1*4096,bn2+1*64, nullptr,B1,
        Wm1+2*4096,bm1+2*64,Wm2+2*4096,bm2+2*64, B0, NP, N);
    gather_slots_k<true><<<gaN,WG,0,stream>>>(cur_ds,sl_ds,CAP_DS,uppool,B0,B2,N);

    // ---- N2: node2 (h2[uppool], B2) -> g=B3
    mlp2_rt<64,true,false,true><<<gN,WG,0,stream>>>(
        B1,uppool,B2, Wn1+2*8192,bn1+2*64,Wn2+2*4096,bn2+2*64, nullptr,B3,N);

    // ---- M3: msg3 over g[downpool] -> HPa
    mlp2_rt<64,false,false,true><<<gNP,WG,0,stream>>>(
        B3,downpool,nullptr, Wm1+3*4096,bm1+3*64,Wm2+3*4096,bm2+3*64, nullptr,HPa,NP);
    gather_slots_k<false><<<gaNP,WG,0,stream>>>(cur_pp,sl_pp,CAP_PP,nullptr,HPa,B2,NP);

    // ---- F_n3m4: node3(g[downpool],B2) -> hp1=HPb ; msg4=HPa
    mlp2_fused<64,true,false,true,64,false,true><<<gNP,WG,0,stream>>>(
        B3,downpool,B2, Wn1+3*8192,bn1+3*64,Wn2+3*4096,bn2+3*64, nullptr,HPb,
        Wm1+4*4096,bm1+4*64,Wm2+4*4096,bm2+4*64, HPa, NP, NP);
    gather_slots_k<false><<<gaNP,WG,0,stream>>>(cur_pp,sl_pp,CAP_PP,nullptr,HPa,B2,NP);

    // ---- F_n4m5: node4(hp1,B2) -> hp2=HPa ; msg5=HPb (same-row overwrite, safe)
    mlp2_fused<64,true,false,false,64,false,true><<<gNP,WG,0,stream>>>(
        HPb,nullptr,B2, Wn1+4*8192,bn1+4*64,Wn2+4*4096,bn2+4*64, nullptr,HPa,
        Wm1+5*4096,bm1+5*64,Wm2+5*4096,bm2+5*64, HPb, NP, NP);
    gather_slots_k<true><<<gaNP,WG,0,stream>>>(cur_us,sl_us,CAP_US,downpool,HPb,B2,NP);

    // ---- F_n5m6: node5(hp2[downpool],B2) -> g'=HPb ; msg6=B3
    mlp2_fused<64,true,false,true,64,false,true><<<gNP,WG,0,stream>>>(
        HPa,downpool,B2, Wn1+5*8192,bn1+5*64,Wn2+5*4096,bn2+5*64, nullptr,HPb,
        Wm1+6*4096,bm1+6*64,Wm2+6*4096,bm2+6*64, B3, NP, NP);
    gather_slots_k<true><<<gaN,WG,0,stream>>>(cur_fine,sl_fine,CAP_FINE,uppool,B3,B2,N);

    // ---- F_n6m7: node6(g'[uppool],B2,+skip B1) -> h7=B0 ; msg7=B3
    mlp2_fused<64,true,true,true,64,false,true><<<gN,WG,0,stream>>>(
        HPb,uppool,B2, Wn1+6*8192,bn1+6*64,Wn2+6*4096,bn2+6*64, B1,B0,
        Wm1+7*4096,bm1+7*64,Wm2+7*4096,bm2+7*64, B3, N, N);
    gather_slots_k<false><<<gaN,WG,0,stream>>>(cur_fine,sl_fine,CAP_FINE,nullptr,B3,B2,N);

    // ---- F_n7dec: node7(h7,B2,+skip B1) -> (no out1) ; decode -> d_out
    mlp2_fused<64,true,true,false,2,false,false><<<gN,WG,0,stream>>>(
        B0,nullptr,B2, Wn1+7*8192,bn1+7*64,Wn2+7*4096,bn2+7*64, B1,nullptr,
        Wd1,bd1,Wd2,bd2, (float*)d_out, N, N);
}